// Round 1
// baseline (275.982 us; speedup 1.0000x reference)
//
#include <hip/hip_runtime.h>
#include <math.h>

// FastWeightsClassifier on MI355X.
// B=64 blocks (1 batch each), 1024 threads. W in VGPRs, history HS + xu in LDS.
// Factored fast-weight: A_t = ETA * sum_{s<t} LAM^{t-1-s} hs_s hs_s^T, so
// Ah = sum_s [ETA*LAM^d * (hs_s . hs0)] * hs_s  -- O(t*H) per step, no A matrix.

#define BB 64
#define TT 64
#define EE 128
#define HH 256
#define HEADN 100
#define NCLSN 10

#define HS_STRIDE 264                      // pad 256->264 floats: P3 column reads <=2-way banks
#define HS_OFF 0                           // 64*264 = 16896 floats (embL[64*128] aliases start, time-disjoint)
#define XU_OFF (64*HS_STRIDE)              // 16384 floats
#define H_OFF  (XU_OFF + TT*HH)            // 256
#define HS0_OFF (H_OFF + HH)               // 256
#define U_OFF  (HS0_OFF + HH)              // 256
#define G_OFF  (U_OFF + HH)                // 256
#define B_OFF  (G_OFF + HH)                // 256
#define GW_OFF (B_OFF + HH)                // 64
#define LP_OFF (GW_OFF + 64)               // 64
#define WS_OFF (LP_OFF + 64)               // 16
#define WQ_OFF (WS_OFF + 16)               // 16
#define IDS_OFF (WQ_OFF + 16)              // 64 (ints)
#define HID_OFF (IDS_OFF + 64)             // 128
#define W2_OFF (HID_OFF + 128)             // 1008
#define B1_OFF (W2_OFF + 1008)             // 104
#define LDS_FLOATS (B1_OFF + 104)          // 36024 floats = 144096 B (< 160 KiB)

__device__ __forceinline__ float dot4(float4 w, float4 v, float acc) {
    acc = fmaf(w.x, v.x, acc);
    acc = fmaf(w.y, v.y, acc);
    acc = fmaf(w.z, v.z, acc);
    acc = fmaf(w.w, v.w, acc);
    return acc;
}

__global__ __launch_bounds__(1024, 4)
void FastWeightsClassifier_54589034332373_kernel(
        const int* __restrict__ x_ids, const float* __restrict__ emb,
        const float* __restrict__ U_w, const float* __restrict__ W_w,
        const float* __restrict__ ln_g, const float* __restrict__ ln_b,
        const float* __restrict__ w1, const float* __restrict__ b1,
        const float* __restrict__ w2, const float* __restrict__ b2,
        float* __restrict__ out)
{
    extern __shared__ __align__(16) float lds[];
    const int t = threadIdx.x;
    const int b = blockIdx.x;

    float* HS   = lds + HS_OFF;
    float* xuL  = lds + XU_OFF;
    float* hL   = lds + H_OFF;
    float* hs0  = lds + HS0_OFF;
    float* uL   = lds + U_OFF;
    float* gL   = lds + G_OFF;
    float* bL   = lds + B_OFF;
    float* gw   = lds + GW_OFF;
    float* LP   = lds + LP_OFF;
    float* wsm  = lds + WS_OFF;
    float* wsq  = lds + WQ_OFF;
    int*   ids  = (int*)(lds + IDS_OFF);
    float* hid  = lds + HID_OFF;
    float* w2L  = lds + W2_OFF;
    float* b1L  = lds + B1_OFF;
    float* embL = lds;                      // aliases HS region; dead before HS first write

    // ---- init ----
    if (t < HH) { gL[t] = ln_g[t]; bL[t] = ln_b[t]; hL[t] = 0.0f; }
    if (t < TT) { ids[t] = x_ids[b*TT + t]; LP[t] = 0.5f * powf(0.9f, (float)t); }
    if (t < HEADN) b1L[t] = b1[t];
    if (t < NCLSN*HEADN) w2L[t] = w2[t];
    __syncthreads();

    // ---- stage emb rows for this batch ----
    {
        int tt = t >> 4, q = t & 15;
        int row = ids[tt];
        float4 e0 = *(const float4*)&emb[row*EE + 8*q];
        float4 e1 = *(const float4*)&emb[row*EE + 8*q + 4];
        *(float4*)&embL[tt*EE + 8*q]     = e0;
        *(float4*)&embL[tt*EE + 8*q + 4] = e1;
    }
    __syncthreads();

    // ---- precompute xu[t][i] = sum_e U[i][e]*x_t[e] into LDS ----
    {
        const int iX = t >> 2, eX = t & 3;
        const int cbX = 32*eX, rotX = 8*eX;         // rotation -> distinct bank groups
        float4 U4[8];
        #pragma unroll
        for (int kk = 0; kk < 8; ++kk) {
            int col = cbX + ((4*kk + rotX) & 31);
            U4[kk] = *(const float4*)&U_w[iX*EE + col];
        }
        for (int tt = 0; tt < TT; ++tt) {
            float a = 0.0f;
            #pragma unroll
            for (int kk = 0; kk < 8; ++kk) {
                int col = cbX + ((4*kk + rotX) & 31);
                float4 ev = *(const float4*)&embL[tt*EE + col];
                a = dot4(U4[kk], ev, a);
            }
            a += __shfl_xor(a, 1);
            a += __shfl_xor(a, 2);
            if (eX == 0) xuL[tt*HH + iX] = a;
        }
    }
    __syncthreads();

    // ---- stage W into registers: thread owns rows r8 and r8+128, cols piece p8 ----
    const int r8 = t >> 3, p8 = t & 7;
    const int cb = 32*p8, rot = 4*p8;
    float4 W0[8], W1[8];
    #pragma unroll
    for (int kk = 0; kk < 8; ++kk) {
        int col = cb + ((4*kk + rot) & 31);
        W0[kk] = *(const float4*)&W_w[r8*HH + col];
        W1[kk] = *(const float4*)&W_w[(r8+128)*HH + col];
    }

    const int i4 = t >> 2, sc = t & 3;
    const int lane = t & 63, wv = t >> 6;

    // ---- recurrence ----
    for (int cur = 0; cur < TT; ++cur) {
        // P1: u = W*h + xu; hs0 = relu(u)
        float a0 = 0.0f, a1 = 0.0f;
        #pragma unroll
        for (int kk = 0; kk < 8; ++kk) {
            int col = cb + ((4*kk + rot) & 31);
            float4 hv = *(const float4*)&hL[col];
            a0 = dot4(W0[kk], hv, a0);
            a1 = dot4(W1[kk], hv, a1);
        }
        a0 += __shfl_xor(a0, 1); a1 += __shfl_xor(a1, 1);
        a0 += __shfl_xor(a0, 2); a1 += __shfl_xor(a1, 2);
        a0 += __shfl_xor(a0, 4); a1 += __shfl_xor(a1, 4);
        if (p8 == 0) {
            float u0 = a0 + xuL[cur*HH + r8];
            float u1 = a1 + xuL[cur*HH + r8 + 128];
            uL[r8] = u0;           uL[r8+128] = u1;
            hs0[r8] = fmaxf(u0, 0.0f); hs0[r8+128] = fmaxf(u1, 0.0f);
        }
        __syncthreads();

        // P2: gw[s] = ETA*LAM^(cur-1-s) * (hs_s . hs0)
        if (r8 < cur) {
            float g = 0.0f;
            #pragma unroll
            for (int kk = 0; kk < 8; ++kk) {
                int col = cb + ((4*kk + rot) & 31);
                float4 hr = *(const float4*)&HS[r8*HS_STRIDE + col];
                float4 h0 = *(const float4*)&hs0[col];
                g = dot4(hr, h0, g);
            }
            g += __shfl_xor(g, 1);
            g += __shfl_xor(g, 2);
            g += __shfl_xor(g, 4);
            if (p8 == 0) gw[r8] = g * LP[cur - 1 - r8];
        }
        __syncthreads();

        // P3: Ah[i] = sum_s gw[s]*HS[s][i]; s_val; wave LN partial sums
        float ah = 0.0f;
        for (int s = sc; s < cur; s += 4)
            ah = fmaf(gw[s], HS[s*HS_STRIDE + i4], ah);
        ah += __shfl_xor(ah, 1);
        ah += __shfl_xor(ah, 2);
        float sv = uL[i4] + ah;
        float s1 = sv, s2 = sv * sv;
        #pragma unroll
        for (int m = 1; m < 64; m <<= 1) { s1 += __shfl_xor(s1, m); s2 += __shfl_xor(s2, m); }
        if (lane == 0) { wsm[wv] = s1; wsq[wv] = s2; }
        __syncthreads();

        // P4: layernorm finalize (redundant on all threads), hs append
        float S1 = 0.0f, S2 = 0.0f;
        #pragma unroll
        for (int w = 0; w < 16; ++w) { S1 += wsm[w]; S2 += wsq[w]; }
        float mean = S1 * (1.0f/1024.0f);             // sums are 4x-duplicated over 256 rows
        float var  = S2 * (1.0f/1024.0f) - mean*mean;
        float rstd = rsqrtf(var + 1e-5f);
        float hsv  = fmaxf(fmaf(gL[i4] * (sv - mean), rstd, bL[i4]), 0.0f);
        if (sc == 0) { hL[i4] = hsv; HS[cur*HS_STRIDE + i4] = hsv; }
        __syncthreads();
    }

    // ---- head: hidden = relu(h @ w1^T + b1); out = hidden @ w2^T + b2 ----
    {
        if (r8 < HEADN) {
            float acc = 0.0f;
            #pragma unroll
            for (int kk = 0; kk < 8; ++kk) {
                int col = cb + ((4*kk + rot) & 31);
                float4 wv1 = *(const float4*)&w1[r8*HH + col];
                float4 hv  = *(const float4*)&hL[col];
                acc = dot4(wv1, hv, acc);
            }
            acc += __shfl_xor(acc, 1);
            acc += __shfl_xor(acc, 2);
            acc += __shfl_xor(acc, 4);
            if (p8 == 0) hid[r8] = fmaxf(acc + b1L[r8], 0.0f);
        }
        __syncthreads();
        if (t < 160) {
            int j2 = t >> 4, l16 = t & 15;
            float o = 0.0f;
            for (int k = l16; k < HEADN; k += 16)
                o = fmaf(hid[k], w2L[j2*HEADN + k], o);
            o += __shfl_xor(o, 1);
            o += __shfl_xor(o, 2);
            o += __shfl_xor(o, 4);
            o += __shfl_xor(o, 8);
            if (l16 == 0) out[b*NCLSN + j2] = o + b2[j2];
        }
    }
}

extern "C" void kernel_launch(void* const* d_in, const int* in_sizes, int n_in,
                              void* d_out, int out_size, void* d_ws, size_t ws_size,
                              hipStream_t stream) {
    const int*   x_ids = (const int*)  d_in[0];
    const float* emb   = (const float*)d_in[1];
    const float* U_w   = (const float*)d_in[2];
    const float* W_w   = (const float*)d_in[3];
    const float* ln_g  = (const float*)d_in[4];
    const float* ln_b  = (const float*)d_in[5];
    const float* hw1   = (const float*)d_in[6];
    const float* hb1   = (const float*)d_in[7];
    const float* hw2   = (const float*)d_in[8];
    const float* hb2   = (const float*)d_in[9];
    float* out = (float*)d_out;

    size_t shmem = (size_t)LDS_FLOATS * sizeof(float);
    hipFuncSetAttribute((const void*)FastWeightsClassifier_54589034332373_kernel,
                        hipFuncAttributeMaxDynamicSharedMemorySize, (int)shmem);
    FastWeightsClassifier_54589034332373_kernel<<<dim3(BB), dim3(1024), shmem, stream>>>(
        x_ids, emb, U_w, W_w, ln_g, ln_b, hw1, hb1, hw2, hb2, out);
}

// Round 2
// 199.319 us; speedup vs baseline: 1.3846x; 1.3846x over previous
//
#include <hip/hip_runtime.h>
#include <math.h>

// FastWeightsClassifier on MI355X — round 2.
// B=64 blocks (1 batch each), 512 threads (8 waves). W in VGPRs (128/thread,
// no spill under __launch_bounds__(512,2) -> 256 VGPR cap). History HS + xu in LDS.
// Factored fast-weight: Ah = sum_s [ETA*LAM^d * (hs_s . hs0)] * hs_s.
// xu = x @ U^T hoisted to a one-shot UE = emb @ U^T kernel (d_ws), gathered per block.

#define TT 64
#define HH 256
#define HEADN 100
#define NCLSN 10
#define HS_STRIDE 264

// LDS float offsets
#define HS_OFF   0                          // 65 rows x 264 = 17160 (row 0 = zeros; row s+1 = hs_s)
#define XU_OFF   (HS_OFF + 65*HS_STRIDE)    // 17160
#define HS0_OFF  (XU_OFF + TT*HH)           // 33544
#define UL_OFF   (HS0_OFF + HH)             // 33800
#define GW_OFF   (UL_OFF + HH)              // 34056
#define LP_OFF   (GW_OFF + 64)              // 34120
#define WSM_OFF  (LP_OFF + 64)              // 34184
#define WSQ_OFF  (WSM_OFF + 8)              // 34192
#define IDS_OFF  (WSQ_OFF + 8)              // 34200 (ints)
#define HID_OFF  (IDS_OFF + 64)             // 34264
#define W2_OFF   (HID_OFF + 104)            // 34368
#define B1_OFF   (W2_OFF + 1000)            // 35368
#define LDS_FLOATS (B1_OFF + 104)           // 35472 floats = 141888 B (< 160 KiB)

__device__ __forceinline__ float dot4(float4 w, float4 v, float acc) {
    acc = fmaf(w.x, v.x, acc);
    acc = fmaf(w.y, v.y, acc);
    acc = fmaf(w.z, v.z, acc);
    acc = fmaf(w.w, v.w, acc);
    return acc;
}

// ---- prologue: UE[v][i] = sum_e U[i][e] * emb[v][e]  (128 x 256) ----
__global__ __launch_bounds__(256)
void fw_ue_kernel(const float* __restrict__ U_w, const float* __restrict__ emb,
                  float* __restrict__ UE)
{
    __shared__ float ev[128];
    const int v = blockIdx.x, i = threadIdx.x;
    if (i < 32) ((float4*)ev)[i] = ((const float4*)(emb + v*128))[i];
    __syncthreads();
    float acc = 0.0f;
    #pragma unroll
    for (int k = 0; k < 32; ++k)
        acc = dot4(((const float4*)(U_w + i*128))[k], ((const float4*)ev)[k], acc);
    UE[v*HH + i] = acc;
}

__global__ __launch_bounds__(512, 2)
void FastWeightsClassifier_54589034332373_kernel(
        const int* __restrict__ x_ids, const float* __restrict__ UE,
        const float* __restrict__ W_w,
        const float* __restrict__ ln_g, const float* __restrict__ ln_b,
        const float* __restrict__ w1, const float* __restrict__ b1,
        const float* __restrict__ w2, const float* __restrict__ b2,
        float* __restrict__ out)
{
    extern __shared__ __align__(16) float lds[];
    const int t = threadIdx.x;
    const int b = blockIdx.x;

    float* HS  = lds + HS_OFF;
    float* xuL = lds + XU_OFF;
    float* hs0 = lds + HS0_OFF;
    float* uL  = lds + UL_OFF;
    float* gw  = lds + GW_OFF;
    float* LP  = lds + LP_OFF;
    float* wsm = lds + WSM_OFF;
    float* wsq = lds + WSQ_OFF;
    int*   ids = (int*)(lds + IDS_OFF);
    float* hid = lds + HID_OFF;
    float* w2L = lds + W2_OFF;
    float* b1L = lds + B1_OFF;

    const int r  = t >> 1, p  = t & 1;   // P1/head decomposition (row, col-half)
    const int s8 = t >> 3, c8 = t & 7;   // P2 decomposition (history row, col-piece)
    const int i2 = r,      sc = p;       // P3 decomposition (component, s-parity)
    const int lane = t & 63, wv = t >> 6;

    // ---- init ----
    if (t < TT) { ids[t] = x_ids[b*TT + t]; LP[t] = 0.5f * powf(0.9f, (float)t); }
    if (t < HH) HS[t] = 0.0f;                            // row 0 = zero h
    if (t < 104) b1L[t] = (t < HEADN) ? b1[t] : 0.0f;
    for (int k = t; k < NCLSN*HEADN; k += 512) w2L[k] = w2[k];
    const float gq = ln_g[i2], bq = ln_b[i2];

    // ---- stage W into registers: thread owns row r, col-half p (128 floats) ----
    float4 W4[32];
    {
        const float* wrow = W_w + r*HH + 128*p;
        #pragma unroll
        for (int k = 0; k < 32; ++k) W4[k] = ((const float4*)wrow)[k];
    }
    __syncthreads();

    // ---- gather xu rows from UE (needs ids) ----
    {
        const int tt = t >> 3, cc = t & 7;
        const float* src = UE + ids[tt]*HH + 32*cc;
        float* dst = xuL + tt*HH + 32*cc;
        #pragma unroll
        for (int k = 0; k < 8; ++k) ((float4*)dst)[k] = ((const float4*)src)[k];
    }
    __syncthreads();

    // ---- recurrence ----
    for (int cur = 0; cur < TT; ++cur) {
        // P1: u = W*h + xu; hs0 = relu(u).  h = HS row cur.
        {
            const float* hrow = HS + cur*HS_STRIDE + 128*p;
            float a = 0.0f;
            #pragma unroll
            for (int k = 0; k < 32; ++k)
                a = dot4(W4[k], ((const float4*)hrow)[k], a);
            a += __shfl_xor(a, 1);
            if (p == 0) {
                float u = a + xuL[cur*HH + r];
                uL[r]  = u;
                hs0[r] = fmaxf(u, 0.0f);
            }
        }
        __syncthreads();

        // P2: gw[s] = ETA*LAM^(cur-1-s) * (hs_s . hs0)
        if (s8 < cur) {
            const float* hsrow = HS + (s8+1)*HS_STRIDE;
            float g = 0.0f;
            #pragma unroll
            for (int k = 0; k < 8; ++k) {
                const int col = 32*c8 + ((4*k + 4*c8) & 31);   // rotate: spread banks
                g = dot4(*(const float4*)(hsrow + col), *(const float4*)(hs0 + col), g);
            }
            g += __shfl_xor(g, 1);
            g += __shfl_xor(g, 2);
            g += __shfl_xor(g, 4);
            if (c8 == 0) gw[s8] = g * LP[cur - 1 - s8];
        }
        __syncthreads();

        // P3: Ah[i] = sum_s gw[s]*hs_s[i]; sv = u + Ah; wave LN partials
        float sv;
        {
            float ah = 0.0f;
            for (int s = sc; s < cur; s += 2)
                ah = fmaf(gw[s], HS[(s+1)*HS_STRIDE + i2], ah);
            ah += __shfl_xor(ah, 1);
            sv = uL[i2] + ah;
            float s1 = sv, s2 = sv * sv;
            #pragma unroll
            for (int m = 1; m < 64; m <<= 1) { s1 += __shfl_xor(s1, m); s2 += __shfl_xor(s2, m); }
            if (lane == 0) { wsm[wv] = s1; wsq[wv] = s2; }
        }
        __syncthreads();

        // P4: LN finalize (redundant on all threads); append hs to HS row cur+1
        {
            float S1 = 0.0f, S2 = 0.0f;
            #pragma unroll
            for (int w = 0; w < 8; ++w) { S1 += wsm[w]; S2 += wsq[w]; }
            const float mean = S1 * (1.0f/512.0f);      // each i counted twice over 512 threads
            const float var  = S2 * (1.0f/512.0f) - mean*mean;
            const float rstd = rsqrtf(var + 1e-5f);
            const float hsv  = fmaxf(fmaf(gq * (sv - mean), rstd, bq), 0.0f);
            if (sc == 0) HS[(cur+1)*HS_STRIDE + i2] = hsv;
        }
        __syncthreads();
    }

    // ---- head: hidden = relu(h @ w1^T + b1); out = hidden @ w2^T + b2 ----
    const float* hfin = HS + TT*HS_STRIDE;              // final hs = row 64
    if (r < HEADN) {
        const float* w1r = w1 + r*HH + 128*p;
        const float* hp  = hfin + 128*p;
        float acc = 0.0f;
        #pragma unroll
        for (int k = 0; k < 32; ++k)
            acc = dot4(((const float4*)w1r)[k], ((const float4*)hp)[k], acc);
        acc += __shfl_xor(acc, 1);
        if (p == 0) hid[r] = fmaxf(acc + b1L[r], 0.0f);
    }
    __syncthreads();
    if (t < 160) {
        const int j = t >> 4, l16 = t & 15;
        float o = 0.0f;
        for (int k = l16; k < HEADN; k += 16)
            o = fmaf(hid[k], w2L[j*HEADN + k], o);
        o += __shfl_xor(o, 1);
        o += __shfl_xor(o, 2);
        o += __shfl_xor(o, 4);
        o += __shfl_xor(o, 8);
        if (l16 == 0) out[b*NCLSN + j] = o + b2[j];
    }
}

extern "C" void kernel_launch(void* const* d_in, const int* in_sizes, int n_in,
                              void* d_out, int out_size, void* d_ws, size_t ws_size,
                              hipStream_t stream) {
    const int*   x_ids = (const int*)  d_in[0];
    const float* emb   = (const float*)d_in[1];
    const float* U_w   = (const float*)d_in[2];
    const float* W_w   = (const float*)d_in[3];
    const float* ln_g  = (const float*)d_in[4];
    const float* ln_b  = (const float*)d_in[5];
    const float* hw1   = (const float*)d_in[6];
    const float* hb1   = (const float*)d_in[7];
    const float* hw2   = (const float*)d_in[8];
    const float* hb2   = (const float*)d_in[9];
    float* out = (float*)d_out;
    float* UE  = (float*)d_ws;              // 128*256*4 = 131072 B

    fw_ue_kernel<<<dim3(128), dim3(256), 0, stream>>>(U_w, emb, UE);

    size_t shmem = (size_t)LDS_FLOATS * sizeof(float);
    hipFuncSetAttribute((const void*)FastWeightsClassifier_54589034332373_kernel,
                        hipFuncAttributeMaxDynamicSharedMemorySize, (int)shmem);
    FastWeightsClassifier_54589034332373_kernel<<<dim3(64), dim3(512), shmem, stream>>>(
        x_ids, UE, W_w, ln_g, ln_b, hw1, hb1, hw2, hb2, out);
}

// Round 3
// 186.745 us; speedup vs baseline: 1.4779x; 1.0673x over previous
//
#include <hip/hip_runtime.h>
#include <math.h>

// FastWeightsClassifier on MI355X — round 3.
// B=64 blocks (1 batch each, 1 block/CU), 512 threads (8 waves).
// W in VGPRs: 128 floats/thread, __launch_bounds__(512,1) -> cap 512 VGPR,
// plus an asm "+v" anchor so the compiler cannot rematerialize the loads
// inside the recurrence (round-2 failure mode: VGPR_Count=96, W reloaded
// from L2 every step).
// Factored fast-weight: Ah = sum_s [ETA*LAM^d * (hs_s . hs0)] * hs_s.
// xu = x @ U^T hoisted to one-shot UE = emb @ U^T kernel (d_ws).

#define TT 64
#define HH 256
#define HEADN 100
#define NCLSN 10
#define HS_STRIDE 264

// LDS float offsets
#define HS_OFF   0                          // 65 rows x 264 (row 0 = zeros; row s+1 = hs_s)
#define XU_OFF   (HS_OFF + 65*HS_STRIDE)    // 17160
#define HS0_OFF  (XU_OFF + TT*HH)           // 33544
#define UL_OFF   (HS0_OFF + HH)             // 33800
#define GW_OFF   (UL_OFF + HH)              // 34056
#define LP_OFF   (GW_OFF + 64)              // 34120
#define WSM_OFF  (LP_OFF + 64)              // 34184
#define WSQ_OFF  (WSM_OFF + 8)              // 34192
#define IDS_OFF  (WSQ_OFF + 8)              // 34200 (ints)
#define HID_OFF  (IDS_OFF + 64)             // 34264
#define W2_OFF   (HID_OFF + 104)            // 34368
#define B1_OFF   (W2_OFF + 1000)            // 35368
#define LDS_FLOATS (B1_OFF + 104)           // 35472 floats = 141888 B (< 160 KiB)

__device__ __forceinline__ float dot4(float4 w, float4 v, float acc) {
    acc = fmaf(w.x, v.x, acc);
    acc = fmaf(w.y, v.y, acc);
    acc = fmaf(w.z, v.z, acc);
    acc = fmaf(w.w, v.w, acc);
    return acc;
}

// ---- prologue: UE[v][i] = sum_e U[i][e] * emb[v][e]  (128 x 256) ----
__global__ __launch_bounds__(256)
void fw_ue_kernel(const float* __restrict__ U_w, const float* __restrict__ emb,
                  float* __restrict__ UE)
{
    __shared__ float ev[128];
    const int v = blockIdx.x, i = threadIdx.x;
    if (i < 32) ((float4*)ev)[i] = ((const float4*)(emb + v*128))[i];
    __syncthreads();
    float a0 = 0.0f, a1 = 0.0f;
    #pragma unroll
    for (int k = 0; k < 32; k += 2) {
        a0 = dot4(((const float4*)(U_w + i*128))[k],   ((const float4*)ev)[k],   a0);
        a1 = dot4(((const float4*)(U_w + i*128))[k+1], ((const float4*)ev)[k+1], a1);
    }
    UE[v*HH + i] = a0 + a1;
}

__global__ __launch_bounds__(512, 1)
void FastWeightsClassifier_54589034332373_kernel(
        const int* __restrict__ x_ids, const float* __restrict__ UE,
        const float* __restrict__ W_w,
        const float* __restrict__ ln_g, const float* __restrict__ ln_b,
        const float* __restrict__ w1, const float* __restrict__ b1,
        const float* __restrict__ w2, const float* __restrict__ b2,
        float* __restrict__ out)
{
    extern __shared__ __align__(16) float lds[];
    const int t = threadIdx.x;
    const int b = blockIdx.x;

    float* HS  = lds + HS_OFF;
    float* xuL = lds + XU_OFF;
    float* hs0 = lds + HS0_OFF;
    float* uL  = lds + UL_OFF;
    float* gw  = lds + GW_OFF;
    float* LP  = lds + LP_OFF;
    float* wsm = lds + WSM_OFF;
    float* wsq = lds + WSQ_OFF;
    int*   ids = (int*)(lds + IDS_OFF);
    float* hid = lds + HID_OFF;
    float* w2L = lds + W2_OFF;
    float* b1L = lds + B1_OFF;

    const int r  = t >> 1, p  = t & 1;   // P1/head decomposition (row, col-half)
    const int s8 = t >> 3, c8 = t & 7;   // P2 decomposition (history row, col-piece)
    const int i2 = r,      sc = p;       // P3 decomposition (component, s-parity)
    const int lane = t & 63, wv = t >> 6;

    // ---- init ----
    if (t < TT) { ids[t] = x_ids[b*TT + t]; LP[t] = 0.5f * powf(0.9f, (float)t); }
    if (t < HH) HS[t] = 0.0f;                            // row 0 = zero h
    if (t < 104) b1L[t] = (t < HEADN) ? b1[t] : 0.0f;
    for (int k = t; k < NCLSN*HEADN; k += 512) w2L[k] = w2[k];
    const float gq = ln_g[i2], bq = ln_b[i2];

    // ---- stage W into registers: thread owns row r, col-half p (128 floats) ----
    float4 W4[32];
    {
        const float* wrow = W_w + r*HH + 128*p;
        #pragma unroll
        for (int k = 0; k < 32; ++k) W4[k] = ((const float4*)wrow)[k];
    }
    // Anchor: make W4 asm-defined so the compiler cannot rematerialize the
    // global loads inside the recurrence loop (round-2 failure mode).
    #pragma unroll
    for (int k = 0; k < 32; ++k)
        asm volatile("" : "+v"(W4[k].x), "+v"(W4[k].y), "+v"(W4[k].z), "+v"(W4[k].w));
    __syncthreads();

    // ---- gather xu rows from UE (needs ids) ----
    {
        const int tt = t >> 3, cc = t & 7;
        const float* src = UE + ids[tt]*HH + 32*cc;
        float* dst = xuL + tt*HH + 32*cc;
        #pragma unroll
        for (int k = 0; k < 8; ++k) ((float4*)dst)[k] = ((const float4*)src)[k];
    }
    __syncthreads();

    // ---- recurrence ----
    for (int cur = 0; cur < TT; ++cur) {
        // P1: u = W*h + xu; hs0 = relu(u).  h = HS row cur.
        {
            const float* hrow = HS + cur*HS_STRIDE + 128*p;
            float a0 = 0.0f, a1 = 0.0f, a2 = 0.0f, a3 = 0.0f;
            #pragma unroll
            for (int k = 0; k < 32; k += 4) {
                a0 = dot4(W4[k],   ((const float4*)hrow)[k],   a0);
                a1 = dot4(W4[k+1], ((const float4*)hrow)[k+1], a1);
                a2 = dot4(W4[k+2], ((const float4*)hrow)[k+2], a2);
                a3 = dot4(W4[k+3], ((const float4*)hrow)[k+3], a3);
            }
            float a = (a0 + a1) + (a2 + a3);
            a += __shfl_xor(a, 1);
            if (p == 0) {
                float u = a + xuL[cur*HH + r];
                uL[r]  = u;
                hs0[r] = fmaxf(u, 0.0f);
            }
        }
        __syncthreads();

        // P2: gw[s] = ETA*LAM^(cur-1-s) * (hs_s . hs0)
        if (s8 < cur) {
            const float* hsrow = HS + (s8+1)*HS_STRIDE;
            float g0 = 0.0f, g1 = 0.0f;
            #pragma unroll
            for (int k = 0; k < 8; k += 2) {
                const int col0 = 32*c8 + ((4*k     + 4*c8) & 31);
                const int col1 = 32*c8 + ((4*(k+1) + 4*c8) & 31);
                g0 = dot4(*(const float4*)(hsrow + col0), *(const float4*)(hs0 + col0), g0);
                g1 = dot4(*(const float4*)(hsrow + col1), *(const float4*)(hs0 + col1), g1);
            }
            float g = g0 + g1;
            g += __shfl_xor(g, 1);
            g += __shfl_xor(g, 2);
            g += __shfl_xor(g, 4);
            if (c8 == 0) gw[s8] = g * LP[cur - 1 - s8];
        }
        __syncthreads();

        // P3: Ah[i] = sum_s gw[s]*hs_s[i]; sv = u + Ah; wave LN partials
        float sv;
        {
            float ah0 = 0.0f, ah1 = 0.0f;
            int s = sc;
            for (; s + 2 < cur; s += 4) {
                ah0 = fmaf(gw[s],   HS[(s+1)*HS_STRIDE + i2], ah0);
                ah1 = fmaf(gw[s+2], HS[(s+3)*HS_STRIDE + i2], ah1);
            }
            for (; s < cur; s += 2)
                ah0 = fmaf(gw[s], HS[(s+1)*HS_STRIDE + i2], ah0);
            float ah = ah0 + ah1;
            ah += __shfl_xor(ah, 1);
            sv = uL[i2] + ah;
            float s1 = sv, s2 = sv * sv;
            #pragma unroll
            for (int m = 1; m < 64; m <<= 1) { s1 += __shfl_xor(s1, m); s2 += __shfl_xor(s2, m); }
            if (lane == 0) { wsm[wv] = s1; wsq[wv] = s2; }
        }
        __syncthreads();

        // P4: LN finalize (redundant on all threads); append hs to HS row cur+1
        {
            float S1 = 0.0f, S2 = 0.0f;
            #pragma unroll
            for (int w = 0; w < 8; ++w) { S1 += wsm[w]; S2 += wsq[w]; }
            const float mean = S1 * (1.0f/512.0f);      // each i counted twice over 512 threads
            const float var  = S2 * (1.0f/512.0f) - mean*mean;
            const float rstd = rsqrtf(var + 1e-5f);
            const float hsv  = fmaxf(fmaf(gq * (sv - mean), rstd, bq), 0.0f);
            if (sc == 0) HS[(cur+1)*HS_STRIDE + i2] = hsv;
        }
        __syncthreads();
    }

    // ---- head: hidden = relu(h @ w1^T + b1); out = hidden @ w2^T + b2 ----
    const float* hfin = HS + TT*HS_STRIDE;              // final hs = row 64
    if (r < HEADN) {
        const float* w1r = w1 + r*HH + 128*p;
        const float* hp  = hfin + 128*p;
        float a0 = 0.0f, a1 = 0.0f;
        #pragma unroll
        for (int k = 0; k < 32; k += 2) {
            a0 = dot4(((const float4*)w1r)[k],   ((const float4*)hp)[k],   a0);
            a1 = dot4(((const float4*)w1r)[k+1], ((const float4*)hp)[k+1], a1);
        }
        float acc = a0 + a1;
        acc += __shfl_xor(acc, 1);
        if (p == 0) hid[r] = fmaxf(acc + b1L[r], 0.0f);
    }
    __syncthreads();
    if (t < 160) {
        const int j = t >> 4, l16 = t & 15;
        float o = 0.0f;
        for (int k = l16; k < HEADN; k += 16)
            o = fmaf(hid[k], w2L[j*HEADN + k], o);
        o += __shfl_xor(o, 1);
        o += __shfl_xor(o, 2);
        o += __shfl_xor(o, 4);
        o += __shfl_xor(o, 8);
        if (l16 == 0) out[b*NCLSN + j] = o + b2[j];
    }
}

extern "C" void kernel_launch(void* const* d_in, const int* in_sizes, int n_in,
                              void* d_out, int out_size, void* d_ws, size_t ws_size,
                              hipStream_t stream) {
    const int*   x_ids = (const int*)  d_in[0];
    const float* emb   = (const float*)d_in[1];
    const float* U_w   = (const float*)d_in[2];
    const float* W_w   = (const float*)d_in[3];
    const float* ln_g  = (const float*)d_in[4];
    const float* ln_b  = (const float*)d_in[5];
    const float* hw1   = (const float*)d_in[6];
    const float* hb1   = (const float*)d_in[7];
    const float* hw2   = (const float*)d_in[8];
    const float* hb2   = (const float*)d_in[9];
    float* out = (float*)d_out;
    float* UE  = (float*)d_ws;              // 128*256*4 = 131072 B

    fw_ue_kernel<<<dim3(128), dim3(256), 0, stream>>>(U_w, emb, UE);

    size_t shmem = (size_t)LDS_FLOATS * sizeof(float);
    hipFuncSetAttribute((const void*)FastWeightsClassifier_54589034332373_kernel,
                        hipFuncAttributeMaxDynamicSharedMemorySize, (int)shmem);
    FastWeightsClassifier_54589034332373_kernel<<<dim3(64), dim3(512), shmem, stream>>>(
        x_ids, UE, W_w, ln_g, ln_b, hw1, hb1, hw2, hb2, out);
}